// Round 1
// baseline (899.452 us; speedup 1.0000x reference)
//
#include <hip/hip_runtime.h>
#include <hip/hip_bf16.h>

// Problem: MultiHeadAttention  B=2, S=2048, D=1024, H=16, dk=64
// out0 = context @ Wo + bo        [B,S,1024]  fp32  (4,194,304 elems)
// out1 = attention_weights        [B,H,S,S]   fp32  (134,217,728 elems)

#define SEQ   2048
#define DMODEL 1024
#define NH    16
#define DKH   64

typedef __attribute__((ext_vector_type(8))) short  short8;
typedef __attribute__((ext_vector_type(4))) float  floatx4;

__device__ __forceinline__ short f2bf(float f) {
    __hip_bfloat16 h = __float2bfloat16(f);
    return *reinterpret_cast<short*>(&h);
}

// ---------------- fp32 -> bf16 elementwise convert ----------------
__global__ void conv_f32_bf16(const float* __restrict__ src, short* __restrict__ dst, int n4) {
    int i = blockIdx.x * blockDim.x + threadIdx.x;
    if (i < n4) {
        float4 v = reinterpret_cast<const float4*>(src)[i];
        short4 o;
        o.x = f2bf(v.x); o.y = f2bf(v.y); o.z = f2bf(v.z); o.w = f2bf(v.w);
        reinterpret_cast<short4*>(dst)[i] = o;
    }
}

// ---------------- W [K,N] fp32 -> Wt [N,K] bf16 (transpose) ----------------
__global__ void conv_wt(const float* __restrict__ W, short* __restrict__ Wt) {
    int t = blockIdx.x * blockDim.x + threadIdx.x;   // 0..1M-1
    int k = t >> 10, n = t & 1023;
    Wt[n * 1024 + k] = f2bf(W[t]);
}

// ---------------- GEMM: A[4096,1024]bf16 @ Wt^T + bias ----------------
// Bt is [N=1024][K=1024] (B^T layout, k-contiguous -> matches B-operand frag)
// mode 0: store bf16 per-head [B,H,S,64]   (q, k)
// mode 2: store bf16 per-head transposed [B,H,64,S]  (v)
// mode 3: store fp32 row-major [4096,1024] (final output)
__global__ __launch_bounds__(256, 4) void gemm_bf16(
    const short* __restrict__ A, const short* __restrict__ Bt,
    const float* __restrict__ bias, void* __restrict__ dst, int mode)
{
    __shared__ __align__(16) short As[128 * 40];
    __shared__ __align__(16) short Bs[128 * 40];
    int tid = threadIdx.x;
    int wave = tid >> 6, lane = tid & 63, quad = lane >> 4, l15 = lane & 15;
    int wy = wave >> 1, wx = wave & 1;
    int bm = blockIdx.y, bn = blockIdx.x;

    floatx4 acc[4][4];
    for (int i = 0; i < 4; i++) for (int j = 0; j < 4; j++) acc[i][j] = (floatx4){0.f, 0.f, 0.f, 0.f};

    for (int kb = 0; kb < 32; kb++) {
        for (int c = 0; c < 2; c++) {
            int ch = tid * 2 + c;                 // 0..511
            int row = ch >> 2, kq = (ch & 3) * 8;
            *(short8*)&As[row * 40 + kq] = *(const short8*)&A [(size_t)(bm * 128 + row) * 1024 + kb * 32 + kq];
            *(short8*)&Bs[row * 40 + kq] = *(const short8*)&Bt[(size_t)(bn * 128 + row) * 1024 + kb * 32 + kq];
        }
        __syncthreads();
        short8 ar[4], br[4];
        for (int mt = 0; mt < 4; mt++) ar[mt] = *(const short8*)&As[(wy * 64 + mt * 16 + l15) * 40 + quad * 8];
        for (int nt = 0; nt < 4; nt++) br[nt] = *(const short8*)&Bs[(wx * 64 + nt * 16 + l15) * 40 + quad * 8];
        for (int mt = 0; mt < 4; mt++)
            for (int nt = 0; nt < 4; nt++)
                acc[mt][nt] = __builtin_amdgcn_mfma_f32_16x16x32_bf16(ar[mt], br[nt], acc[mt][nt], 0, 0, 0);
        __syncthreads();
    }

    for (int mt = 0; mt < 4; mt++) {
        for (int nt = 0; nt < 4; nt++) {
            int col = bn * 128 + wx * 64 + nt * 16 + l15;
            float bb = bias[col];
            for (int r = 0; r < 4; r++) {
                int row = bm * 128 + wy * 64 + mt * 16 + quad * 4 + r;
                float v = acc[mt][nt][r] + bb;
                if (mode == 3) {
                    ((float*)dst)[(size_t)row * 1024 + col] = v;
                } else {
                    int b = row >> 11, s = row & 2047, h = col >> 6, dk = col & 63;
                    size_t idx;
                    if (mode == 0) idx = ((size_t)(b * NH + h) * SEQ + s) * DKH + dk;
                    else           idx = ((size_t)(b * NH + h) * DKH + dk) * SEQ + s;
                    ((short*)dst)[idx] = f2bf(v);
                }
            }
        }
    }
}

// ---------------- fused attention: scores+softmax+weights-out+context ----------------
// grid: (S/64 q-tiles, B*H). block 256 = 4 waves.
// Pass 1: accumulate rowsum(exp) and unnormalized ctx = exp(S) @ V.
// Pass 2: recompute scores, write normalized weights fp32 to d_out.
__global__ __launch_bounds__(256, 2) void attn(
    const short* __restrict__ Q,    // [B,H,S,64] bf16
    const short* __restrict__ K,    // [B,H,S,64] bf16
    const short* __restrict__ Vt,   // [B,H,64,S] bf16
    float* __restrict__ wout,       // [B,H,S,S] fp32
    short* __restrict__ ctx)        // [B*S,1024] bf16
{
    __shared__ __align__(16) short Qs [64 * 72];
    __shared__ __align__(16) short Ks [128 * 72];
    __shared__ __align__(16) short Vts[64 * 136];
    __shared__ __align__(16) short Ps [64 * 136];
    __shared__ float partial[4][64];
    __shared__ float rowsum[64];
    __shared__ float rinv[64];

    int tid = threadIdx.x, wave = tid >> 6, lane = tid & 63, quad = lane >> 4, l15 = lane & 15;
    int qt = blockIdx.x, bh = blockIdx.y;
    int b = bh >> 4, h = bh & 15;
    const short* qb  = Q  + ((size_t)bh * SEQ + qt * 64) * DKH;
    const short* kbp = K  + (size_t)bh * SEQ * DKH;
    const short* vtb = Vt + (size_t)bh * DKH * SEQ;

    for (int c = 0; c < 2; c++) {                   // load Q tile [64][64]
        int ch = tid * 2 + c; int row = ch >> 3, d = (ch & 7) * 8;
        *(short8*)&Qs[row * 72 + d] = *(const short8*)&qb[row * 64 + d];
    }
    if (tid < 64) rowsum[tid] = 0.f;

    floatx4 cacc[4];
    for (int i = 0; i < 4; i++) cacc[i] = (floatx4){0.f, 0.f, 0.f, 0.f};
    int nbase = wave * 32;

    // ---- pass 1 ----
    for (int kb = 0; kb < SEQ / 128; kb++) {
        __syncthreads();   // prev-iter consumers of Ks/Vts/partial done
        for (int c = 0; c < 4; c++) {               // K tile [128][64]
            int ch = tid * 4 + c; int row = ch >> 3, d = (ch & 7) * 8;
            *(short8*)&Ks[row * 72 + d] = *(const short8*)&kbp[(size_t)(kb * 128 + row) * 64 + d];
        }
        for (int c = 0; c < 4; c++) {               // Vt tile [64][128]
            int ch = tid * 4 + c; int dd = ch >> 4, kq = (ch & 15) * 8;
            *(short8*)&Vts[dd * 136 + kq] = *(const short8*)&vtb[(size_t)dd * SEQ + kb * 128 + kq];
        }
        __syncthreads();

        floatx4 sacc[4][2];
        for (int mt = 0; mt < 4; mt++) for (int nt = 0; nt < 2; nt++) sacc[mt][nt] = (floatx4){0.f, 0.f, 0.f, 0.f};
        for (int kt = 0; kt < 2; kt++) {
            short8 ar[4], br[2];
            for (int mt = 0; mt < 4; mt++) ar[mt] = *(const short8*)&Qs[(mt * 16 + l15) * 72 + kt * 32 + quad * 8];
            for (int nt = 0; nt < 2; nt++) br[nt] = *(const short8*)&Ks[(nbase + nt * 16 + l15) * 72 + kt * 32 + quad * 8];
            for (int mt = 0; mt < 4; mt++)
                for (int nt = 0; nt < 2; nt++)
                    sacc[mt][nt] = __builtin_amdgcn_mfma_f32_16x16x32_bf16(ar[mt], br[nt], sacc[mt][nt], 0, 0, 0);
        }
        // exp (no max-subtraction: scores ~N(0,1), fp32-safe), P to LDS, row partials
        for (int mt = 0; mt < 4; mt++) {
            for (int r = 0; r < 4; r++) {
                float e0 = __expf(sacc[mt][0][r] * 0.125f);
                float e1 = __expf(sacc[mt][1][r] * 0.125f);
                int row = mt * 16 + quad * 4 + r;
                Ps[row * 136 + nbase + l15]      = f2bf(e0);
                Ps[row * 136 + nbase + 16 + l15] = f2bf(e1);
                float s = e0 + e1;
                s += __shfl_xor(s, 1, 64); s += __shfl_xor(s, 2, 64);
                s += __shfl_xor(s, 4, 64); s += __shfl_xor(s, 8, 64);
                if (l15 == 0) partial[wave][row] = s;
            }
        }
        __syncthreads();
        if (tid < 64) rowsum[tid] += partial[0][tid] + partial[1][tid] + partial[2][tid] + partial[3][tid];
        // ctx += P @ V   (P in A-layout from LDS, Vt rows are B-operand k-contiguous)
        for (int kt = 0; kt < 4; kt++) {
            short8 pa = *(const short8*)&Ps[(wave * 16 + l15) * 136 + kt * 32 + quad * 8];
            for (int nt = 0; nt < 4; nt++) {
                short8 vb = *(const short8*)&Vts[(nt * 16 + l15) * 136 + kt * 32 + quad * 8];
                cacc[nt] = __builtin_amdgcn_mfma_f32_16x16x32_bf16(pa, vb, cacc[nt], 0, 0, 0);
            }
        }
    }
    __syncthreads();
    if (tid < 64) rinv[tid] = 1.f / rowsum[tid];
    __syncthreads();

    // write ctx (normalized), bf16, layout [b*S+s][h*64+d]
    for (int nt = 0; nt < 4; nt++) {
        for (int r = 0; r < 4; r++) {
            int row = wave * 16 + quad * 4 + r;
            int qg = qt * 64 + row;
            float v = cacc[nt][r] * rinv[row];
            ctx[((size_t)(b * SEQ + qg)) * DMODEL + h * DKH + nt * 16 + l15] = f2bf(v);
        }
    }

    // ---- pass 2: recompute scores, write normalized weights ----
    float* wb = wout + ((size_t)bh * SEQ + qt * 64) * SEQ;
    for (int kb = 0; kb < SEQ / 128; kb++) {
        __syncthreads();
        for (int c = 0; c < 4; c++) {
            int ch = tid * 4 + c; int row = ch >> 3, d = (ch & 7) * 8;
            *(short8*)&Ks[row * 72 + d] = *(const short8*)&kbp[(size_t)(kb * 128 + row) * 64 + d];
        }
        __syncthreads();
        floatx4 sacc[4][2];
        for (int mt = 0; mt < 4; mt++) for (int nt = 0; nt < 2; nt++) sacc[mt][nt] = (floatx4){0.f, 0.f, 0.f, 0.f};
        for (int kt = 0; kt < 2; kt++) {
            short8 ar[4], br[2];
            for (int mt = 0; mt < 4; mt++) ar[mt] = *(const short8*)&Qs[(mt * 16 + l15) * 72 + kt * 32 + quad * 8];
            for (int nt = 0; nt < 2; nt++) br[nt] = *(const short8*)&Ks[(nbase + nt * 16 + l15) * 72 + kt * 32 + quad * 8];
            for (int mt = 0; mt < 4; mt++)
                for (int nt = 0; nt < 2; nt++)
                    sacc[mt][nt] = __builtin_amdgcn_mfma_f32_16x16x32_bf16(ar[mt], br[nt], sacc[mt][nt], 0, 0, 0);
        }
        for (int mt = 0; mt < 4; mt++) {
            for (int r = 0; r < 4; r++) {
                int row = mt * 16 + quad * 4 + r;
                float ri = rinv[row];
                wb[(size_t)row * SEQ + kb * 128 + nbase + l15]      = __expf(sacc[mt][0][r] * 0.125f) * ri;
                wb[(size_t)row * SEQ + kb * 128 + nbase + 16 + l15] = __expf(sacc[mt][1][r] * 0.125f) * ri;
            }
        }
    }
}

extern "C" void kernel_launch(void* const* d_in, const int* in_sizes, int n_in,
                              void* d_out, int out_size, void* d_ws, size_t ws_size,
                              hipStream_t stream) {
    const float* query = (const float*)d_in[0];
    const float* key_  = (const float*)d_in[1];
    const float* value = (const float*)d_in[2];
    const float* Wq = (const float*)d_in[3];  const float* bq = (const float*)d_in[4];
    const float* Wk = (const float*)d_in[5];  const float* bk = (const float*)d_in[6];
    const float* Wv = (const float*)d_in[7];  const float* bv = (const float*)d_in[8];
    const float* Wo = (const float*)d_in[9];  const float* bo = (const float*)d_in[10];

    char* ws = (char*)d_ws;
    const size_t MB = 1ull << 20;
    short* xq  = (short*)(ws +  0 * MB);   // [4096,1024] bf16
    short* xk  = (short*)(ws +  8 * MB);
    short* xv  = (short*)(ws + 16 * MB);
    short* wtq = (short*)(ws + 24 * MB);   // [1024(n),1024(k)] bf16
    short* wtk = (short*)(ws + 26 * MB);
    short* wtv = (short*)(ws + 28 * MB);
    short* wto = (short*)(ws + 30 * MB);
    short* qh  = (short*)(ws + 32 * MB);   // [B,H,S,64] bf16
    short* kh  = (short*)(ws + 40 * MB);
    short* vth = (short*)(ws + 48 * MB);   // [B,H,64,S] bf16
    short* ctx = (short*)(ws + 56 * MB);   // [4096,1024] bf16

    float* out0 = (float*)d_out;
    float* wout = out0 + (size_t)4194304;

    conv_f32_bf16<<<4096, 256, 0, stream>>>(query, xq, 1048576);
    conv_f32_bf16<<<4096, 256, 0, stream>>>(key_,  xk, 1048576);
    conv_f32_bf16<<<4096, 256, 0, stream>>>(value, xv, 1048576);
    conv_wt<<<4096, 256, 0, stream>>>(Wq, wtq);
    conv_wt<<<4096, 256, 0, stream>>>(Wk, wtk);
    conv_wt<<<4096, 256, 0, stream>>>(Wv, wtv);
    conv_wt<<<4096, 256, 0, stream>>>(Wo, wto);

    dim3 gg(8, 32);
    gemm_bf16<<<gg, 256, 0, stream>>>(xq, wtq, bq, qh,  0);
    gemm_bf16<<<gg, 256, 0, stream>>>(xk, wtk, bk, kh,  0);
    gemm_bf16<<<gg, 256, 0, stream>>>(xv, wtv, bv, vth, 2);

    attn<<<dim3(SEQ / 64, 32), 256, 0, stream>>>(qh, kh, vth, wout, ctx);

    gemm_bf16<<<gg, 256, 0, stream>>>(ctx, wto, bo, out0, 3);
}